// Round 1
// baseline (196.741 us; speedup 1.0000x reference)
//
#include <hip/hip_runtime.h>

#define HW 192
#define DD 512
#define GG 64
#define PP 64
#define SLAB 98304  // 192*512 i8 bytes per slab

typedef __attribute__((ext_vector_type(4))) int intx4;

__device__ __forceinline__ unsigned int pk4(float a, float b, float c, float d) {
  int qa = (int)rintf(a), qb = (int)rintf(b), qc = (int)rintf(c), qd = (int)rintf(d);
  return (unsigned)(qa & 255) | ((unsigned)(qb & 255) << 8) |
         ((unsigned)(qc & 255) << 16) | ((unsigned)(qd & 255) << 24);
}

// L2-normalize over channels -> int8 (q = rint(127*v)), fragment-linear ws:
// ws[slab][kb2(8)][R(12)][lane(64)][16B]
//   pos = R*16 + (lane&15), bytes = channels kb2*64 + (lane>>4)*16 .. +15.
// This is the per-lane operand order of mfma_i32_16x16x64_i8 (16B/lane,
// k = quad*16 + j — natural extension of the HW-validated 16x16x32 family),
// so the GEMM loads fragments straight from global (1KB contiguous per
// wave-load). Block = (slab, 16-pos chunk), 512 threads; r8-proven structure.
__global__ __launch_bounds__(512, 2) void norm_kernel(
    const float* __restrict__ gal, const float* __restrict__ prob,
    unsigned char* __restrict__ ws) {
  int b = blockIdx.x;  // 0..1535
  int s = b / 12;      // slab 0..127
  int q = b - s * 12;  // pos chunk (= R) 0..11
  const float* in = (s < GG) ? (gal + (size_t)s * DD * HW)
                             : (prob + (size_t)(s - GG) * DD * HW);
  unsigned char* out = ws + (size_t)s * SLAB;
  int pos0 = q * 16;
  int t = threadIdx.x;

  __shared__ float T[16][524];   // 33.5 KB, [pos][c]
  __shared__ float sqa[128][17];
  __shared__ float sq2[16][17];
  __shared__ float scl[16];

  {
    int cq = t >> 2;   // 0..127
    int quad = t & 3;  // 0..3
    float p0 = 0.f, p1 = 0.f, p2 = 0.f, p3 = 0.f;
#pragma unroll
    for (int cb = 0; cb < 4; ++cb) {
      int c = cb * 128 + cq;
      const float4 v = *(const float4*)(in + (size_t)c * HW + pos0 + quad * 4);
      T[quad * 4 + 0][c] = v.x;
      T[quad * 4 + 1][c] = v.y;
      T[quad * 4 + 2][c] = v.z;
      T[quad * 4 + 3][c] = v.w;
      p0 += v.x * v.x; p1 += v.y * v.y; p2 += v.z * v.z; p3 += v.w * v.w;
    }
    sqa[cq][quad * 4 + 0] = p0;
    sqa[cq][quad * 4 + 1] = p1;
    sqa[cq][quad * 4 + 2] = p2;
    sqa[cq][quad * 4 + 3] = p3;
  }
  __syncthreads();
  if (t < 256) {
    int g2 = t >> 4, pos = t & 15;
    float v = 0.f;
#pragma unroll
    for (int r = 0; r < 8; ++r) v += sqa[g2 * 8 + r][pos];
    sq2[g2][pos] = v;
  }
  __syncthreads();
  if (t < 16) {
    float v = 0.f;
#pragma unroll
    for (int r = 0; r < 16; ++r) v += sq2[r][t];
    scl[t] = 1.f / fmaxf(sqrtf(v), 1e-12f);
  }
  __syncthreads();

  {
    int kb2 = t >> 6;    // 0..7 (uniform per wave)
    int lane = t & 63;
    int l4 = lane >> 4;  // k-quarter 0..3
    int pos = lane & 15; // 0..15
    float sc = scl[pos] * 127.f;
    int base = kb2 * 64 + l4 * 16;
    const float4 r0 = *(const float4*)&T[pos][base + 0];
    const float4 r1 = *(const float4*)&T[pos][base + 4];
    const float4 r2 = *(const float4*)&T[pos][base + 8];
    const float4 r3 = *(const float4*)&T[pos][base + 12];
    uint4 u;
    u.x = pk4(r0.x * sc, r0.y * sc, r0.z * sc, r0.w * sc);
    u.y = pk4(r1.x * sc, r1.y * sc, r1.z * sc, r1.w * sc);
    u.z = pk4(r2.x * sc, r2.y * sc, r2.z * sc, r2.w * sc);
    u.w = pk4(r3.x * sc, r3.y * sc, r3.z * sc, r3.w * sc);
    *(uint4*)(out + (size_t)kb2 * 12288 + (size_t)q * 1024 + (size_t)lane * 16) = u;
  }
}

// One block per (g,p), int8 via mfma_i32_16x16x64_i8 (2x K per inst vs fp8
// 16x16x32 => MFMA-issue term halves; ordinary v4i32 operands => no spills,
// unlike the scaled-MFMA attempts r9/r10). Memory behavior byte-identical to
// r8: no LDS / no barriers in K-loop, 12 x 1KB contiguous wave-loads per kb2,
// register double-buffered. Epilogue: max-pool in int32 (monotone), one
// float convert * (1/127^2) at the end.
//
// R11: XCD-aware bijective swizzle. Dispatch round-robins blockIdx across the
// 8 XCDs, scattering each 8x8 supertile over all 8 per-XCD L2s -> every XCD
// touches ~all 128 slabs (12.6MB >> 4MiB L2), fragment loads see L3-class
// latency (~600-900cy) that the 1-kb2-deep prefetch (~734cy MFMA) can't hide
// -> MfmaUtil 33%. Remap bid = (bid0%8)*512 + bid0/8 (4096%8==0, bijective):
// XCD x owns supertiles 8x..8x+7 -> 8 g-slabs resident all kernel + 8 p-slabs
// at a time (~1.6MB << 4MiB). 64 blocks/XCD resident = exactly 1 supertile.
__global__ __launch_bounds__(256, 2) void qaconv_gemm(
    const unsigned char* __restrict__ ws, const float* __restrict__ fcw,
    const float* __restrict__ bnw, const float* __restrict__ bnb,
    const float* __restrict__ bnm, const float* __restrict__ bnv,
    const float* __restrict__ fcb, const float* __restrict__ lw,
    const float* __restrict__ lb, const float* __restrict__ lm,
    const float* __restrict__ lv, float* __restrict__ out) {
  int bid0 = blockIdx.x;
  int bid = ((bid0 & 7) << 9) + (bid0 >> 3);  // XCD-contiguous supertiles
  int sb = bid >> 6, li = bid & 63;  // 8x8 supertiles for L2 locality
  int g = ((sb >> 3) << 3) + (li >> 3);
  int p = ((sb & 7) << 3) + (li & 7);
  const unsigned char* Bsrc = ws + (size_t)g * SLAB;         // galt[g] frags
  const unsigned char* Asrc = ws + (size_t)(GG + p) * SLAB;  // kern[p] frags

  __shared__ float colpart[2][HW];
  __shared__ float rowpart[2][HW];
  __shared__ float redbuf[4][2];

  int tid = threadIdx.x;
  int lane = tid & 63;
  int wave = tid >> 6;
  int wi = wave >> 1, wj = wave & 1;
  int l15 = lane & 15, l4 = lane >> 4;

  intx4 acc[6][6];
#pragma unroll
  for (int a = 0; a < 6; ++a)
#pragma unroll
    for (int c = 0; c < 6; ++c) acc[a][c] = (intx4){0, 0, 0, 0};

  // frag (it) lives at R = wi*6+it (A) / wj*6+jt (B)
  const unsigned char* aP = Asrc + (size_t)(wi * 6) * 1024 + (size_t)lane * 16;
  const unsigned char* bP = Bsrc + (size_t)(wj * 6) * 1024 + (size_t)lane * 16;

#define LOADF(AD, BD, KB)                                                 \
  do {                                                                    \
    _Pragma("unroll") for (int it_ = 0; it_ < 6; ++it_) {                 \
      AD[it_] = *(const intx4*)(aP + (size_t)(KB)*12288 + it_ * 1024);    \
      BD[it_] = *(const intx4*)(bP + (size_t)(KB)*12288 + it_ * 1024);    \
    }                                                                     \
  } while (0)

#define MFMAB(AD, BD)                                                     \
  do {                                                                    \
    _Pragma("unroll") for (int jt_ = 0; jt_ < 6; ++jt_) {                 \
      intx4 bb = BD[jt_];                                                 \
      _Pragma("unroll") for (int it_ = 0; it_ < 6; ++it_)                 \
          acc[it_][jt_] = __builtin_amdgcn_mfma_i32_16x16x64_i8(          \
              AD[it_], bb, acc[it_][jt_], 0, 0, 0);                       \
    }                                                                     \
  } while (0)

  intx4 aC[6], bC[6], aN[6], bN[6];
  LOADF(aC, bC, 0);
#pragma unroll 1
  for (int kb2 = 0; kb2 < 8; kb2 += 2) {
    LOADF(aN, bN, kb2 + 1);
    MFMAB(aC, bC);
    if (kb2 < 6) LOADF(aC, bC, kb2 + 2);
    MFMAB(aN, bN);
  }
#undef LOADF
#undef MFMAB

  // ---- epilogue: dual max-pool in int32 ----
  // C/D layout: i = wi*96 + it*16 + l4*4 + r ; j = wj*96 + jt*16 + l15
  const float inv = 1.f / 16129.f;  // 1/127^2
  int cm[6];
  int rm[6][4];
#pragma unroll
  for (int jt = 0; jt < 6; ++jt) cm[jt] = -2147483647;
#pragma unroll
  for (int it = 0; it < 6; ++it)
#pragma unroll
    for (int r = 0; r < 4; ++r) rm[it][r] = -2147483647;
#pragma unroll
  for (int it = 0; it < 6; ++it)
#pragma unroll
    for (int jt = 0; jt < 6; ++jt)
#pragma unroll
      for (int r = 0; r < 4; ++r) {
        int v = acc[it][jt][r];
        cm[jt] = max(cm[jt], v);
        rm[it][r] = max(rm[it][r], v);
      }

#pragma unroll
  for (int jt = 0; jt < 6; ++jt) {
    int v = cm[jt];
    v = max(v, __shfl_xor(v, 16, 64));
    v = max(v, __shfl_xor(v, 32, 64));
    if (lane < 16) colpart[wi][wj * 96 + jt * 16 + lane] = (float)v * inv;
  }
#pragma unroll
  for (int it = 0; it < 6; ++it)
#pragma unroll
    for (int r = 0; r < 4; ++r) {
      int v = rm[it][r];
      v = max(v, __shfl_xor(v, 1, 64));
      v = max(v, __shfl_xor(v, 2, 64));
      v = max(v, __shfl_xor(v, 4, 64));
      v = max(v, __shfl_xor(v, 8, 64));
      if (l15 == 0) rowpart[wj][wi * 96 + it * 16 + l4 * 4 + r] = (float)v * inv;
    }
  __syncthreads();

  // ---- fused BN -> fc -> lbn -> sigmoid ----
  float part = 0.f, wpart = 0.f;
  if (tid < HW) {
    float cmax = fmaxf(colpart[0][tid], colpart[1][tid]);  // score[j]
    float rmax = fmaxf(rowpart[0][tid], rowpart[1][tid]);  // score[192+i]
    float w1 = fcw[tid], w2 = fcw[HW + tid];
    part = cmax * w1 + rmax * w2;
    wpart = w1 + w2;
  }
#pragma unroll
  for (int off = 32; off > 0; off >>= 1) {
    part += __shfl_down(part, off, 64);
    wpart += __shfl_down(wpart, off, 64);
  }
  if (lane == 0) { redbuf[wave][0] = part; redbuf[wave][1] = wpart; }
  __syncthreads();
  if (tid == 0) {
    float s = redbuf[0][0] + redbuf[1][0] + redbuf[2][0] + redbuf[3][0];
    float wsum = redbuf[0][1] + redbuf[1][1] + redbuf[2][1] + redbuf[3][1];
    float bnA = bnw[0] * rsqrtf(bnv[0] + 1e-5f);
    float bnB = bnb[0] - bnm[0] * bnA;
    float sc = bnA * s + bnB * wsum + fcb[0];
    float lA = lw[0] * rsqrtf(lv[0] + 1e-5f);
    sc = (sc - lm[0]) * lA + lb[0];
    out[g * PP + p] = 1.f / (1.f + __expf(-sc * 0.1f));
  }
}

extern "C" void kernel_launch(void* const* d_in, const int* in_sizes, int n_in,
                              void* d_out, int out_size, void* d_ws, size_t ws_size,
                              hipStream_t stream) {
  const float* gal  = (const float*)d_in[0];
  const float* prob = (const float*)d_in[1];
  const float* bnw  = (const float*)d_in[2];
  const float* bnb  = (const float*)d_in[3];
  const float* bnm  = (const float*)d_in[4];
  const float* bnv  = (const float*)d_in[5];
  const float* fcw  = (const float*)d_in[6];
  const float* fcb  = (const float*)d_in[7];
  const float* lw   = (const float*)d_in[8];
  const float* lb   = (const float*)d_in[9];
  const float* lm   = (const float*)d_in[10];
  const float* lv   = (const float*)d_in[11];
  unsigned char* ws = (unsigned char*)d_ws;
  float* out = (float*)d_out;

  hipLaunchKernelGGL(norm_kernel, dim3(1536), dim3(512), 0, stream, gal, prob, ws);
  hipLaunchKernelGGL(qaconv_gemm, dim3(GG * PP), dim3(256), 0, stream, ws, fcw,
                     bnw, bnb, bnm, bnv, fcb, lw, lb, lm, lv, out);
}